// Round 12
// baseline (5213.178 us; speedup 1.0000x reference)
//
#include <hip/hip_runtime.h>
#include <hip/hip_bf16.h>

typedef float f32x4 __attribute__((ext_vector_type(4)));
typedef short bf16x8 __attribute__((ext_vector_type(8)));
typedef unsigned int u32x4 __attribute__((ext_vector_type(4)));

#define MFMA16x32(a,b,c) __builtin_amdgcn_mfma_f32_16x16x32_bf16((a),(b),(c),0,0,0)

__device__ __forceinline__ unsigned short f2bf(float f) {
  unsigned u = __float_as_uint(f);
  u += 0x7fffu + ((u >> 16) & 1u);
  return (unsigned short)(u >> 16);
}

// H stores: relaxed agent-scope = write-through past L2 into L3 (no dirty L2
// lines). vmcnt(0) ack => globally visible. Proven R6-R11.
__device__ __forceinline__ void ast16(unsigned short* p, unsigned short v) {
  __hip_atomic_store(p, v, __ATOMIC_RELAXED, __HIP_MEMORY_SCOPE_AGENT);
}

// L1/L2-bypass 16B load as bf16x8 (reads L3 coherence point; pipelined).
__device__ __forceinline__ bf16x8 ld16f(const void* p) {
  bf16x8 r;
  asm volatile("global_load_dwordx4 %0, %1, off sc0 sc1" : "=v"(r) : "v"(p) : "memory");
  return r;
}

// ---------------- workspace layout (bytes) ----------------
#define WS_G1BLOB 0ull
#define WS_G3BLOB 8388608ull
#define WS_WOUTT  25165824ull
#define WS_H1RING 33554432ull
#define WS_SYNC   34078720ull
#define WS_H2ALL  34095104ull

#define SLSTRIDE 8   // u32 per sync slot (32B per block; 128 slots/group = 4KB)

__global__ void k_init(unsigned* __restrict__ p, int n) {
  int i = blockIdx.x * blockDim.x + threadIdx.x;
  for (; i < n; i += gridDim.x * blockDim.x) p[i] = 0u;
}

// ---------------- pack W1h into per-wave B-fragment blob ----------------
__global__ void k_pack_g1(const float* __restrict__ W1, unsigned short* __restrict__ blob) {
  int gtid = blockIdx.x * 256 + threadIdx.x;      // 524288 threads
  int lane = gtid & 63, kk = (gtid >> 6) & 31, w = gtid >> 11;
  int c = lane & 15, q = lane >> 4;
  int g = c >> 2, h = w * 4 + (c & 3);
  bf16x8 s;
#pragma unroll
  for (int j = 0; j < 8; ++j) {
    int k = kk * 32 + q * 8 + j;
    float v = W1[(size_t)g * 5242880u + (size_t)(4096 + k) * 1024u + h];
    ((unsigned short*)&s)[j] = f2bf(v);
  }
  ((bf16x8*)blob)[(size_t)(w * 32 + kk) * 64 + lane] = s;
}

// ---------------- pack W2 (kk<32 -> W2h rows 1024+, kk>=32 -> W2x rows 0..1023) ----------------
__global__ void k_pack_g3(const float* __restrict__ W2, unsigned short* __restrict__ blob) {
  int gtid = blockIdx.x * 256 + threadIdx.x;      // 1048576 threads
  int lane = gtid & 63, kk = (gtid >> 6) & 63, w = gtid >> 12;
  int c = lane & 15, q = lane >> 4;
  int g = c >> 2, h = w * 4 + (c & 3);
  bf16x8 s;
#pragma unroll
  for (int j = 0; j < 8; ++j) {
    int klocal = (kk & 31) * 32 + q * 8 + j;
    int d = (kk < 32) ? (1024 + klocal) : klocal;
    float v = W2[(size_t)g * 2097152u + (size_t)d * 1024u + h];
    ((unsigned short*)&s)[j] = f2bf(v);
  }
  ((bf16x8*)blob)[(size_t)(w * 64 + kk) * 64 + lane] = s;
}

// ---------------- Wout^T bf16 ----------------
__global__ void k_pack_woutT(const float* __restrict__ Wout, unsigned short* __restrict__ wT) {
  int gtid = blockIdx.x * 256 + threadIdx.x;      // 4,194,304 threads
  int k = gtid & 1023, n = gtid >> 10;
  wT[(size_t)n * 1024 + k] = f2bf(Wout[(size_t)k * 4096 + n]);
}

// ---------------- flag-array sync over 128 slots (fence-free) ----------------
__device__ __forceinline__ void wait_slots(const unsigned* __restrict__ slots,
                                           unsigned epoch, unsigned* __restrict__ poison) {
  if (threadIdx.x < 64) {
    unsigned guard = 0;
    for (;;) {
      unsigned v0 = __hip_atomic_load(&slots[threadIdx.x * SLSTRIDE],
                                      __ATOMIC_RELAXED, __HIP_MEMORY_SCOPE_AGENT);
      unsigned v1 = __hip_atomic_load(&slots[(threadIdx.x + 64) * SLSTRIDE],
                                      __ATOMIC_RELAXED, __HIP_MEMORY_SCOPE_AGENT);
      unsigned v = v0 < v1 ? v0 : v1;
      if (__all((int)(v >= epoch))) break;
      __builtin_amdgcn_s_sleep(1);
      if (((++guard) & 1023u) == 0u) {
        if (guard > (1u << 18) ||
            __hip_atomic_load(poison, __ATOMIC_RELAXED, __HIP_MEMORY_SCOPE_AGENT) != 0u) {
          __hip_atomic_store(poison, 1u, __ATOMIC_RELAXED, __HIP_MEMORY_SCOPE_AGENT);
          break;   // fail-visible, never hard-hang
        }
      }
    }
  }
  __syncthreads();
}

// Publish: drain write-through stores (=> visible at L3), block barrier, flag store.
__device__ __forceinline__ void publish_slot(unsigned* __restrict__ slots,
                                             int myslot, unsigned epoch) {
  asm volatile("s_waitcnt vmcnt(0)" ::: "memory");
  __syncthreads();
  if (threadIdx.x == 0) {
    __hip_atomic_store(&slots[myslot * SLSTRIDE], epoch,
                       __ATOMIC_RELAXED, __HIP_MEMORY_SCOPE_AGENT);
  }
}

// ---------------- direct-from-L3 MFMA phase (no LDS) ----------------
// acc[m] += H[rows m*16+c][K-half kh] @ Bw[j].  H row-major [64][1024] bf16.
// 16-deep counted-vmcnt pipeline: 8 loads in flight behind 8 MFMAs.
// sched_barrier(0) after each wait per rule #18 (MFMA must not hoist past it).
__device__ __forceinline__ void phase_direct(const char* __restrict__ Hbase,
                                             int kh, int c, int q,
                                             const bf16x8* __restrict__ Bw,
                                             f32x4 (&acc)[4]) {
  asm volatile("s_waitcnt vmcnt(0)" ::: "memory");  // isolate counted window
  const char* base = Hbase + c * 2048 + kh * 1024 + q * 16;
  bf16x8 v[2][8];
#define ISSUE(BUF, M, JB) \
  _Pragma("unroll") for (int i = 0; i < 8; ++i) \
    v[BUF][i] = ld16f(base + (M) * 32768 + ((JB) * 8 + i) * 64);
#define MM(BUF, M, JB) \
  _Pragma("unroll") for (int i = 0; i < 8; ++i) \
    acc[M] = MFMA16x32(v[BUF][i], Bw[(JB) * 8 + i], acc[M]);
#define W8 asm volatile("s_waitcnt vmcnt(8)" ::: "memory"); __builtin_amdgcn_sched_barrier(0);
#define W0 asm volatile("s_waitcnt vmcnt(0)" ::: "memory"); __builtin_amdgcn_sched_barrier(0);
  ISSUE(0, 0, 0) ISSUE(1, 0, 1)
  W8 MM(0, 0, 0) ISSUE(0, 1, 0)
  W8 MM(1, 0, 1) ISSUE(1, 1, 1)
  W8 MM(0, 1, 0) ISSUE(0, 2, 0)
  W8 MM(1, 1, 1) ISSUE(1, 2, 1)
  W8 MM(0, 2, 0) ISSUE(0, 3, 0)
  W8 MM(1, 2, 1) ISSUE(1, 3, 1)
  W8 MM(0, 3, 0)
  W0 MM(1, 3, 1)
#undef ISSUE
#undef MM
#undef W8
#undef W0
}

// ---------------- persistent recurrent kernel: 256 blocks, K-split pairs ----------------
// G1 (blocks 0..127):   H1(t) -> h1ring[t&3].  Block covers 32 cols (2 tiles).
// G3 (blocks 128..255): H2(t) -> h2all[t].
// wave widx -> col-tile ct=widx>>1, K-half kh=widx&1. A-fragments read DIRECTLY
// from L3 (no LDS staging). Partials via conflict-free lane-major LDS reduce.
__global__ __launch_bounds__(256, 1) void k_lstm(
    const int* __restrict__ tokens, const float* __restrict__ W1,
    const float* __restrict__ b1, const float* __restrict__ b2,
    const unsigned short* __restrict__ g1blob, const unsigned short* __restrict__ g3blob,
    unsigned short* __restrict__ h1ring, unsigned short* __restrict__ h2all,
    float* __restrict__ outF, unsigned* __restrict__ syncbase)
{
  __shared__ float red[2][16][64];       // 8 KB lane-major partial exchange (conflict-free)

  const int tid = threadIdx.x, lane = tid & 63, widx = tid >> 6, bid = blockIdx.x;
  const int c = lane & 15, q = lane >> 4;
  const bool isG1 = bid < 128;
  const int myslot = isG1 ? bid : bid - 128;          // 0..127
  const int ct = widx >> 1, kh = widx & 1;
  const int w = myslot * 2 + ct;                      // 0..255 col-unit (16 cols)
  const int g = c >> 2;
  const int hcol = w * 4 + (c & 3);
  const int h_ew = w * 4 + (lane & 3);

  unsigned* g1slots = syncbase;                       // 128 x 8 u32 (4KB)
  unsigned* g3slots = syncbase + 1024;
  unsigned* poison  = syncbase + 2048;

  // --- preload weight fragments (this wave's K-half only) ---
  bf16x8 Breg[32];
  {
    const bf16x8* blob1 = (const bf16x8*)g1blob;
    const bf16x8* blob3 = (const bf16x8*)g3blob;
    if (isG1) {
#pragma unroll
      for (int j = 0; j < 16; ++j)
        Breg[j] = blob1[(size_t)(w * 32 + kh * 16 + j) * 64 + lane];
    } else {
#pragma unroll
      for (int j = 0; j < 16; ++j) {
        Breg[j]      = blob3[(size_t)(w * 64 + kh * 16 + j) * 64 + lane];        // W2h (phase A)
        Breg[16 + j] = blob3[(size_t)(w * 64 + 32 + kh * 16 + j) * 64 + lane];   // W2x (phase C)
      }
    }
  }
  const float biasv = isG1 ? b1[g * 1024 + hcol] : b2[g * 1024 + hcol];

  float Cst[16];
#pragma unroll
  for (int i = 0; i < 16; ++i) Cst[i] = 0.f;

  // --- G1 kh==0: preload embedding gathers for t=0 ---
  float gv[16];
  if (isG1 && kh == 0) {
#pragma unroll
    for (int m = 0; m < 4; ++m)
#pragma unroll
      for (int r = 0; r < 4; ++r) {
        int b_ = m * 16 + q * 4 + r;
        int tk = tokens[b_ * 256];
        gv[m * 4 + r] = W1[(size_t)g * 5242880u + (size_t)tk * 1024u + hcol];
      }
  }

  f32x4 acc[4];

  if (isG1) {
    // ================= G1 chain =================
#pragma clang loop unroll(disable)
    for (int t = 0; t < 256; ++t) {
      if (t > 0) wait_slots(g1slots, (unsigned)t, poison);   // all H1(t-1) at L3

      int tk2[16];
      if (kh == 0) {
        const int tn = (t < 255) ? t + 1 : 255;
#pragma unroll
        for (int m = 0; m < 4; ++m)
#pragma unroll
          for (int r = 0; r < 4; ++r)
            tk2[m * 4 + r] = tokens[(m * 16 + q * 4 + r) * 256 + tn];
      }

#pragma unroll
      for (int m = 0; m < 4; ++m) acc[m] = (f32x4){0.f, 0.f, 0.f, 0.f};
      if (t > 0)
        phase_direct((const char*)(h1ring + ((t - 1) & 3) * 65536), kh, c, q, &Breg[0], acc);

      if (t >= 4) wait_slots(g3slots, (unsigned)(t - 3), poison);  // ring backpressure

      // K-split partial exchange (lane-major, conflict-free)
      if (kh == 1) {
#pragma unroll
        for (int m = 0; m < 4; ++m)
#pragma unroll
          for (int r = 0; r < 4; ++r) red[ct][m * 4 + r][lane] = acc[m][r];
      }
      __syncthreads();
      if (kh == 0) {
#pragma unroll
        for (int m = 0; m < 4; ++m) {
#pragma unroll
          for (int r = 0; r < 4; ++r) {
            float v = acc[m][r] + red[ct][m * 4 + r][lane] + gv[m * 4 + r] + biasv;
            const int sb = (lane & 48) | (lane & 3);
            float vf = __shfl(v, sb, 64);
            float vi = __shfl(v, sb | 4, 64);
            float vo = __shfl(v, sb | 8, 64);
            float vc = __shfl(v, sb | 12, 64);
            float fg = 1.f / (1.f + __expf(-vf));
            float ig = 1.f / (1.f + __expf(-vi));
            float og = 1.f / (1.f + __expf(-vo));
            float e2 = __expf(2.f * vc);
            float ct_ = (e2 - 1.f) / (e2 + 1.f);
            float Cn = fg * Cst[m * 4 + r] + ig * ct_;
            Cst[m * 4 + r] = Cn;
            float e2c = __expf(2.f * Cn);
            float Hn = og * (e2c - 1.f) / (e2c + 1.f);
            if ((lane & 12) == 0) {
              int row = m * 16 + q * 4 + r;
              ast16(&h1ring[(t & 3) * 65536 + row * 1024 + h_ew], f2bf(Hn));
              if (t == 255) {
                outF[row * 1024 + h_ew] = Hn;           // H1 final
                outF[65536 + row * 1024 + h_ew] = Cn;   // C1 final
              }
            }
          }
        }
      }
      publish_slot(g1slots, myslot, (unsigned)(t + 1));      // H1(t) published

      // prefetch next step's embedding gathers (latency hides under next poll)
      if (kh == 0) {
#pragma unroll
        for (int i = 0; i < 16; ++i)
          gv[i] = W1[(size_t)g * 5242880u + (size_t)tk2[i] * 1024u + hcol];
      }
    }
  } else {
    // ================= G3 chain =================
#pragma clang loop unroll(disable)
    for (int t = 0; t < 256; ++t) {
      // phase C FIRST (early start): H1(t) available since G1 runs ahead
      wait_slots(g1slots, (unsigned)(t + 1), poison);
#pragma unroll
      for (int m = 0; m < 4; ++m)
        acc[m] = (kh == 0) ? (f32x4){biasv, biasv, biasv, biasv}
                           : (f32x4){0.f, 0.f, 0.f, 0.f};
      phase_direct((const char*)(h1ring + (t & 3) * 65536), kh, c, q, &Breg[16], acc);

      if (t > 0) {       // phase A: H2(t-1) @ W2h (own-group barrier)
        wait_slots(g3slots, (unsigned)t, poison);
        phase_direct((const char*)(h2all + (size_t)(t - 1) * 65536), kh, c, q, &Breg[0], acc);
      }

      // K-split partial exchange (lane-major, conflict-free)
      if (kh == 1) {
#pragma unroll
        for (int m = 0; m < 4; ++m)
#pragma unroll
          for (int r = 0; r < 4; ++r) red[ct][m * 4 + r][lane] = acc[m][r];
      }
      __syncthreads();
      if (kh == 0) {
#pragma unroll
        for (int m = 0; m < 4; ++m) {
#pragma unroll
          for (int r = 0; r < 4; ++r) {
            float v = acc[m][r] + red[ct][m * 4 + r][lane];
            const int sb = (lane & 48) | (lane & 3);
            float vf = __shfl(v, sb, 64);
            float vi = __shfl(v, sb | 4, 64);
            float vo = __shfl(v, sb | 8, 64);
            float vc = __shfl(v, sb | 12, 64);
            float fg = 1.f / (1.f + __expf(-vf));
            float ig = 1.f / (1.f + __expf(-vi));
            float og = 1.f / (1.f + __expf(-vo));
            float e2 = __expf(2.f * vc);
            float ct_ = (e2 - 1.f) / (e2 + 1.f);
            float Cn = fg * Cst[m * 4 + r] + ig * ct_;
            Cst[m * 4 + r] = Cn;
            float e2c = __expf(2.f * Cn);
            float Hn = og * (e2c - 1.f) / (e2c + 1.f);
            if ((lane & 12) == 0) {
              int row = m * 16 + q * 4 + r;
              ast16(&h2all[((size_t)t * 64 + row) * 1024 + h_ew], f2bf(Hn));
              if (t == 255) {
                outF[131072 + row * 1024 + h_ew] = Hn;  // H2 final
                outF[196608 + row * 1024 + h_ew] = Cn;  // C2 final
              }
            }
          }
        }
      }
      publish_slot(g3slots, myslot, (unsigned)(t + 1));      // H2(t) published
    }
  }
}

// ---------------- output projection: Y = H2all @ Wout + bout ----------------
__global__ __launch_bounds__(256, 2) void k_gemm_out(
    const unsigned short* __restrict__ A, const unsigned short* __restrict__ Bt,
    const float* __restrict__ bout, float* __restrict__ C)
{
  __shared__ unsigned short As[128 * 32];
  __shared__ unsigned short Bs[128 * 32];
  const int tid = threadIdx.x, lane = tid & 63, wv = tid >> 6;
  const int c = lane & 15, q = lane >> 4;
  const int bn = blockIdx.x & 31, bm = blockIdx.x >> 5;
  const int wm = wv >> 1, wn = wv & 1;

  f32x4 acc[4][4];
#pragma unroll
  for (int m = 0; m < 4; ++m)
#pragma unroll
    for (int n = 0; n < 4; ++n) acc[m][n] = (f32x4){0.f, 0.f, 0.f, 0.f};

  const unsigned short* Abase = A + (size_t)(bm * 128) * 1024;
  const unsigned short* Bbase = Bt + (size_t)(bn * 128) * 1024;

  for (int kt = 0; kt < 32; ++kt) {
    if (kt) __syncthreads();
#pragma unroll
    for (int ch = 0; ch < 2; ++ch) {
      int o = ch * 4096 + tid * 16;
      int row = o >> 6;
      int ks = (o & 63) >> 1;
      *(bf16x8*)&As[o >> 1] = *(const bf16x8*)(Abase + (size_t)row * 1024 + kt * 32 + ks);
      *(bf16x8*)&Bs[o >> 1] = *(const bf16x8*)(Bbase + (size_t)row * 1024 + kt * 32 + ks);
    }
    __syncthreads();
    bf16x8 af[4], bfr[4];
#pragma unroll
    for (int m = 0; m < 4; ++m) af[m] = *(const bf16x8*)&As[(wm * 64 + m * 16 + c) * 32 + q * 8];
#pragma unroll
    for (int n = 0; n < 4; ++n) bfr[n] = *(const bf16x8*)&Bs[(wn * 64 + n * 16 + c) * 32 + q * 8];
#pragma unroll
    for (int m = 0; m < 4; ++m)
#pragma unroll
      for (int n = 0; n < 4; ++n) acc[m][n] = MFMA16x32(af[m], bfr[n], acc[m][n]);
  }

#pragma unroll
  for (int n = 0; n < 4; ++n) {
    int col = bn * 128 + wn * 64 + n * 16 + c;
    float bo = bout[col];
#pragma unroll
    for (int m = 0; m < 4; ++m) {
      int row0 = bm * 128 + wm * 64 + m * 16 + q * 4;
#pragma unroll
      for (int r = 0; r < 4; ++r)
        C[(size_t)(row0 + r) * 4096 + col] = acc[m][n][r] + bo;
    }
  }
}

extern "C" void kernel_launch(void* const* d_in, const int* in_sizes, int n_in,
                              void* d_out, int out_size, void* d_ws, size_t ws_size,
                              hipStream_t stream) {
  const int* tokens = (const int*)d_in[0];
  const float* W1 = (const float*)d_in[1];
  const float* b1 = (const float*)d_in[2];
  const float* W2 = (const float*)d_in[3];
  const float* b2 = (const float*)d_in[4];
  const float* Wout = (const float*)d_in[5];
  const float* bout = (const float*)d_in[6];

  char* ws = (char*)d_ws;
  unsigned short* g1blob = (unsigned short*)(ws + WS_G1BLOB);
  unsigned short* g3blob = (unsigned short*)(ws + WS_G3BLOB);
  unsigned short* woutT  = (unsigned short*)(ws + WS_WOUTT);
  unsigned short* h1ring = (unsigned short*)(ws + WS_H1RING);
  unsigned*       syncb  = (unsigned*)(ws + WS_SYNC);
  unsigned short* h2all  = (unsigned short*)(ws + WS_H2ALL);

  float* outY = (float*)d_out;
  float* outF = outY + 67108864;   // Y then H1,C1,H2,C2

  hipLaunchKernelGGL(k_init, dim3(16), dim3(256), 0, stream, syncb, 4096);
  hipLaunchKernelGGL(k_pack_g1, dim3(2048), dim3(256), 0, stream, W1, g1blob);
  hipLaunchKernelGGL(k_pack_g3, dim3(4096), dim3(256), 0, stream, W2, g3blob);
  hipLaunchKernelGGL(k_pack_woutT, dim3(16384), dim3(256), 0, stream, Wout, woutT);

  hipLaunchKernelGGL(k_lstm, dim3(256), dim3(256), 0, stream,
                     tokens, W1, b1, b2, g1blob, g3blob, h1ring, h2all, outF, syncb);

  hipLaunchKernelGGL(k_gemm_out, dim3(4096), dim3(256), 0, stream, h2all, woutT, bout, outY);
}

// Round 13
// 4638.230 us; speedup vs baseline: 1.1240x; 1.1240x over previous
//
#include <hip/hip_runtime.h>
#include <hip/hip_bf16.h>

typedef float f32x4 __attribute__((ext_vector_type(4)));
typedef short bf16x8 __attribute__((ext_vector_type(8)));

#define MFMA16x32(a,b,c) __builtin_amdgcn_mfma_f32_16x16x32_bf16((a),(b),(c),0,0,0)

__device__ __forceinline__ unsigned short f2bf(float f) {
  unsigned u = __float_as_uint(f);
  u += 0x7fffu + ((u >> 16) & 1u);
  return (unsigned short)(u >> 16);
}

// Write-through relaxed agent stores (bypass L2 -> L3-visible after vmcnt ack).
__device__ __forceinline__ void ast16(unsigned short* p, unsigned short v) {
  __hip_atomic_store(p, v, __ATOMIC_RELAXED, __HIP_MEMORY_SCOPE_AGENT);
}
__device__ __forceinline__ void ast32(float* p, float v) {
  __hip_atomic_store(p, v, __ATOMIC_RELAXED, __HIP_MEMORY_SCOPE_AGENT);
}

// L1/L2-bypass 16B loads (read the L3 coherence point; pipelined).
__device__ __forceinline__ bf16x8 ld16bf(const void* p) {
  bf16x8 r;
  asm volatile("global_load_dwordx4 %0, %1, off sc0 sc1" : "=v"(r) : "v"(p) : "memory");
  return r;
}
__device__ __forceinline__ f32x4 ld16f32(const void* p) {
  f32x4 r;
  asm volatile("global_load_dwordx4 %0, %1, off sc0 sc1" : "=v"(r) : "v"(p) : "memory");
  return r;
}

// ---------------- workspace layout (bytes) ----------------
#define WS_G1BLOB 0ull
#define WS_G3BLOB 8388608ull
#define WS_WOUTT  25165824ull
#define WS_H1RING 33554432ull   // 4 x 128KB
#define WS_SYNC   34078720ull   // 16KB
#define WS_H2ALL  34095104ull   // 32MB
#define WS_X2     67649536ull   // 4 x 4096 x 64 f32 = 4MB

#define SLSTRIDE 8   // u32 per sync slot (32B line per block)

__global__ void k_init(unsigned* __restrict__ p, int n) {
  int i = blockIdx.x * blockDim.x + threadIdx.x;
  for (; i < n; i += gridDim.x * blockDim.x) p[i] = 0u;
}

// ---------------- pack W1h into per-wave B-fragment blob ----------------
__global__ void k_pack_g1(const float* __restrict__ W1, unsigned short* __restrict__ blob) {
  int gtid = blockIdx.x * 256 + threadIdx.x;      // 524288 threads
  int lane = gtid & 63, kk = (gtid >> 6) & 31, w = gtid >> 11;
  int c = lane & 15, q = lane >> 4;
  int g = c >> 2, h = w * 4 + (c & 3);
  bf16x8 s;
#pragma unroll
  for (int j = 0; j < 8; ++j) {
    int k = kk * 32 + q * 8 + j;
    float v = W1[(size_t)g * 5242880u + (size_t)(4096 + k) * 1024u + h];
    ((unsigned short*)&s)[j] = f2bf(v);
  }
  ((bf16x8*)blob)[(size_t)(w * 32 + kk) * 64 + lane] = s;
}

// ---------------- pack W2 (kk<32 -> W2h rows 1024+, kk>=32 -> W2x rows 0..1023) ----------------
__global__ void k_pack_g3(const float* __restrict__ W2, unsigned short* __restrict__ blob) {
  int gtid = blockIdx.x * 256 + threadIdx.x;      // 1048576 threads
  int lane = gtid & 63, kk = (gtid >> 6) & 63, w = gtid >> 12;
  int c = lane & 15, q = lane >> 4;
  int g = c >> 2, h = w * 4 + (c & 3);
  bf16x8 s;
#pragma unroll
  for (int j = 0; j < 8; ++j) {
    int klocal = (kk & 31) * 32 + q * 8 + j;
    int d = (kk < 32) ? (1024 + klocal) : klocal;
    float v = W2[(size_t)g * 2097152u + (size_t)d * 1024u + h];
    ((unsigned short*)&s)[j] = f2bf(v);
  }
  ((bf16x8*)blob)[(size_t)(w * 64 + kk) * 64 + lane] = s;
}

// ---------------- Wout^T bf16 ----------------
__global__ void k_pack_woutT(const float* __restrict__ Wout, unsigned short* __restrict__ wT) {
  int gtid = blockIdx.x * 256 + threadIdx.x;      // 4,194,304 threads
  int k = gtid & 1023, n = gtid >> 10;
  wT[(size_t)n * 1024 + k] = f2bf(Wout[(size_t)k * 4096 + n]);
}

// ---------------- flag-array sync (fence-free, proven R8-R11) ----------------
__device__ __forceinline__ void wait64(const unsigned* __restrict__ slots,
                                       unsigned epoch, unsigned* __restrict__ poison) {
  if (threadIdx.x < 64) {
    unsigned guard = 0;
    for (;;) {
      unsigned v = __hip_atomic_load(&slots[threadIdx.x * SLSTRIDE],
                                     __ATOMIC_RELAXED, __HIP_MEMORY_SCOPE_AGENT);
      if (__all((int)(v >= epoch))) break;
      __builtin_amdgcn_s_sleep(1);
      if (((++guard) & 1023u) == 0u) {
        if (guard > (1u << 18) ||
            __hip_atomic_load(poison, __ATOMIC_RELAXED, __HIP_MEMORY_SCOPE_AGENT) != 0u) {
          __hip_atomic_store(poison, 1u, __ATOMIC_RELAXED, __HIP_MEMORY_SCOPE_AGENT);
          break;   // fail-visible, never hard-hang
        }
      }
    }
  }
  __syncthreads();
}

__device__ __forceinline__ void wait128(const unsigned* __restrict__ slots,
                                        unsigned epoch, unsigned* __restrict__ poison) {
  if (threadIdx.x < 64) {
    unsigned guard = 0;
    for (;;) {
      unsigned v0 = __hip_atomic_load(&slots[threadIdx.x * SLSTRIDE],
                                      __ATOMIC_RELAXED, __HIP_MEMORY_SCOPE_AGENT);
      unsigned v1 = __hip_atomic_load(&slots[(threadIdx.x + 64) * SLSTRIDE],
                                      __ATOMIC_RELAXED, __HIP_MEMORY_SCOPE_AGENT);
      unsigned v = v0 < v1 ? v0 : v1;
      if (__all((int)(v >= epoch))) break;
      __builtin_amdgcn_s_sleep(1);
      if (((++guard) & 1023u) == 0u) {
        if (guard > (1u << 18) ||
            __hip_atomic_load(poison, __ATOMIC_RELAXED, __HIP_MEMORY_SCOPE_AGENT) != 0u) {
          __hip_atomic_store(poison, 1u, __ATOMIC_RELAXED, __HIP_MEMORY_SCOPE_AGENT);
          break;
        }
      }
    }
  }
  __syncthreads();
}

// Publish: drain write-through stores (=> visible at L3), block barrier, flag store.
__device__ __forceinline__ void publish_slot(unsigned* __restrict__ slots,
                                             int myslot, unsigned epoch) {
  asm volatile("s_waitcnt vmcnt(0)" ::: "memory");
  __syncthreads();
  if (threadIdx.x == 0) {
    __hip_atomic_store(&slots[myslot * SLSTRIDE], epoch,
                       __ATOMIC_RELAXED, __HIP_MEMORY_SCOPE_AGENT);
  }
}

// ---------------- stage 128KB H global->LDS in FRAGMENT ORDER ----------------
// Wave widx stages fragment-blocks (m=widx, kk=it): lane loads global 16B at
// row (widx*16+c), k-bytes it*64+q*16; writes LDS at (it*4+widx)*1024+lane*16.
// Both ds_write and later ds_read_b128 are lane-sequential: ZERO bank conflicts.
// Rolling 16-outstanding counted-vmcnt window; 2 reg buffers (64 VGPRs).
__device__ __forceinline__ void stage_H(const unsigned short* __restrict__ Hsrc,
                                        unsigned short* __restrict__ Hs) {
  asm volatile("s_waitcnt vmcnt(0)" ::: "memory");   // isolate counted window
  const int lane = threadIdx.x & 63, widx = threadIdx.x >> 6;
  const int c = lane & 15, q = lane >> 4;
  const char* src = (const char*)Hsrc + (widx * 16 + c) * 2048 + q * 16;
  char* dst = (char*)Hs + widx * 1024 + lane * 16;
  bf16x8 v[2][8];
#define ISS(BUF, IT0) \
  _Pragma("unroll") for (int i = 0; i < 8; ++i) v[BUF][i] = ld16bf(src + ((IT0) + i) * 64);
#define WRB(BUF, IT0) \
  _Pragma("unroll") for (int i = 0; i < 8; ++i) *(bf16x8*)(dst + ((IT0) + i) * 4096) = v[BUF][i];
#define W8 asm volatile("s_waitcnt vmcnt(8)" ::: "memory"); __builtin_amdgcn_sched_barrier(0);
#define W0 asm volatile("s_waitcnt vmcnt(0)" ::: "memory"); __builtin_amdgcn_sched_barrier(0);
  ISS(0, 0) ISS(1, 8)
  W8 WRB(0, 0) ISS(0, 16)
  W8 WRB(1, 8) ISS(1, 24)
  W8 WRB(0, 16)
  W0 WRB(1, 24)
#undef ISS
#undef WRB
#undef W8
#undef W0
}

// fragment read: (m, kk) -> bf16x8 at lane-sequential address (conflict-free)
__device__ __forceinline__ bf16x8 lds_frag(const unsigned short* __restrict__ Hs,
                                           int m, int kk, int lane) {
  return *(const bf16x8*)((const char*)Hs + ((kk * 4 + m) * 64 + lane) * 16);
}

// ---------------- persistent recurrent kernel: 256 blocks, 3 roles ----------------
// G1 (0..63):    layer-1 recurrence. wave = col-unit w=bid*4+widx, full K=1024.
// G2 (64..191):  layer-2 SERIAL chain only: H2(t)=ew(H2(t-1)@W2h + X2(t)).
//                kh-split pairs (w=(bid-64)*2+ct).
// GX (192..255): X2(t)=b2+H1(t)@W2x -> x2ring[t&3] (OFF the serial chain).
__global__ __launch_bounds__(256, 1) void k_lstm(
    const int* __restrict__ tokens, const float* __restrict__ W1,
    const float* __restrict__ b1, const float* __restrict__ b2,
    const unsigned short* __restrict__ g1blob, const unsigned short* __restrict__ g3blob,
    unsigned short* __restrict__ h1ring, unsigned short* __restrict__ h2all,
    float* __restrict__ x2ring, float* __restrict__ outF,
    unsigned* __restrict__ syncbase)
{
  __shared__ unsigned short Hs[65536];   // 128 KB fragment-ordered staging
  __shared__ float red[2][16][64];       // 8 KB lane-major reduce (conflict-free)

  const int tid = threadIdx.x, lane = tid & 63, widx = tid >> 6, bid = blockIdx.x;
  const int c = lane & 15, q = lane >> 4;
  const int g = c >> 2;

  unsigned* g1slots = syncbase;            // 64 x 8 u32
  unsigned* gxslots = syncbase + 512;      // 64 x 8 u32
  unsigned* g2slots = syncbase + 1024;     // 128 x 8 u32
  unsigned* poison  = syncbase + 2048;

  f32x4 acc[4];
  float Cst[16];
#pragma unroll
  for (int i = 0; i < 16; ++i) Cst[i] = 0.f;

  if (bid < 64) {
    // ================= G1: layer-1 recurrence (full-K waves) =================
    const int w = bid * 4 + widx;                 // col-unit 0..255
    const int hcol = w * 4 + (c & 3);
    const int h_ew = w * 4 + (lane & 3);
    bf16x8 Breg[32];
    {
      const bf16x8* blob1 = (const bf16x8*)g1blob;
#pragma unroll
      for (int j = 0; j < 32; ++j)
        Breg[j] = blob1[(size_t)(w * 32 + j) * 64 + lane];
    }
    const float biasv = b1[g * 1024 + hcol];

    float gv[16];
#pragma unroll
    for (int m = 0; m < 4; ++m)
#pragma unroll
      for (int r = 0; r < 4; ++r) {
        int b_ = m * 16 + q * 4 + r;
        int tk = tokens[b_ * 256];
        gv[m * 4 + r] = W1[(size_t)g * 5242880u + (size_t)tk * 1024u + hcol];
      }

#pragma clang loop unroll(disable)
    for (int t = 0; t < 256; ++t) {
      if (t > 0) wait64(g1slots, (unsigned)t, poison);   // all H1(t-1) at L3

#pragma unroll
      for (int m = 0; m < 4; ++m) acc[m] = (f32x4){0.f, 0.f, 0.f, 0.f};
      if (t > 0) {
        stage_H(h1ring + ((t - 1) & 3) * 65536, Hs);
        __syncthreads();
#pragma unroll
        for (int j = 0; j < 32; ++j)
#pragma unroll
          for (int m = 0; m < 4; ++m)
            acc[m] = MFMA16x32(lds_frag(Hs, m, j, lane), Breg[j], acc[m]);
      }
      // ring backpressure: GX must have consumed slot t&3's old content (t-4)
      if (t >= 4) wait64(gxslots, (unsigned)(t - 3), poison);
      else __syncthreads();

#pragma unroll
      for (int m = 0; m < 4; ++m) {
#pragma unroll
        for (int r = 0; r < 4; ++r) {
          float v = acc[m][r] + gv[m * 4 + r] + biasv;
          const int sb = (lane & 48) | (lane & 3);
          float vf = __shfl(v, sb, 64);
          float vi = __shfl(v, sb | 4, 64);
          float vo = __shfl(v, sb | 8, 64);
          float vc = __shfl(v, sb | 12, 64);
          float fg = 1.f / (1.f + __expf(-vf));
          float ig = 1.f / (1.f + __expf(-vi));
          float og = 1.f / (1.f + __expf(-vo));
          float e2 = __expf(2.f * vc);
          float ct_ = (e2 - 1.f) / (e2 + 1.f);
          float Cn = fg * Cst[m * 4 + r] + ig * ct_;
          Cst[m * 4 + r] = Cn;
          float e2c = __expf(2.f * Cn);
          float Hn = og * (e2c - 1.f) / (e2c + 1.f);
          if ((lane & 12) == 0) {
            int row = m * 16 + q * 4 + r;
            ast16(&h1ring[(t & 3) * 65536 + row * 1024 + h_ew], f2bf(Hn));
            if (t == 255) {
              outF[row * 1024 + h_ew] = Hn;           // H1 final
              outF[65536 + row * 1024 + h_ew] = Cn;   // C1 final
            }
          }
        }
      }
      publish_slot(g1slots, bid, (unsigned)(t + 1));     // H1(t) published

      // prefetch next step's embedding gathers (hides under next poll)
      const int tn = (t < 255) ? t + 1 : 255;
#pragma unroll
      for (int m = 0; m < 4; ++m)
#pragma unroll
        for (int r = 0; r < 4; ++r) {
          int b_ = m * 16 + q * 4 + r;
          int tk = tokens[b_ * 256 + tn];
          gv[m * 4 + r] = W1[(size_t)g * 5242880u + (size_t)tk * 1024u + hcol];
        }
    }
  } else if (bid < 192) {
    // ================= G2: layer-2 serial chain (kh-split) =================
    const int ms = bid - 64;                       // 0..127
    const int ct = widx >> 1, kh = widx & 1;
    const int w = ms * 2 + ct;                     // col-unit 0..255
    const int h_ew = w * 4 + (lane & 3);
    bf16x8 Breg[16];                               // W2h, this K-half
    {
      const bf16x8* blob3 = (const bf16x8*)g3blob;
#pragma unroll
      for (int j = 0; j < 16; ++j)
        Breg[j] = blob3[(size_t)(w * 64 + kh * 16 + j) * 64 + lane];
    }

#pragma clang loop unroll(disable)
    for (int t = 0; t < 256; ++t) {
      wait64(gxslots, (unsigned)(t + 1), poison);  // X2(t) ready at L3

      f32x4 x2v[4];
      if (kh == 0) {                               // issue X2 readback early
        const float* xp = x2ring + ((size_t)((t & 3) * 4096 + w * 16 + c)) * 64 + q * 4;
#pragma unroll
        for (int m = 0; m < 4; ++m) x2v[m] = ld16f32(xp + m * 16);
      }

#pragma unroll
      for (int m = 0; m < 4; ++m) acc[m] = (f32x4){0.f, 0.f, 0.f, 0.f};
      if (t > 0) {
        wait128(g2slots, (unsigned)t, poison);     // peers' H2(t-1) published
        stage_H(h2all + (size_t)(t - 1) * 65536, Hs);
        __syncthreads();
#pragma unroll
        for (int j = 0; j < 16; ++j)
#pragma unroll
          for (int m = 0; m < 4; ++m)
            acc[m] = MFMA16x32(lds_frag(Hs, m, kh * 16 + j, lane), Breg[j], acc[m]);
      }
      asm volatile("s_waitcnt vmcnt(0)" ::: "memory");  // x2v complete (t==0 path)
      __builtin_amdgcn_sched_barrier(0);

      // K-split partial exchange (lane-major, conflict-free)
      if (kh == 1) {
#pragma unroll
        for (int m = 0; m < 4; ++m)
#pragma unroll
          for (int r = 0; r < 4; ++r) red[ct][m * 4 + r][lane] = acc[m][r];
      }
      __syncthreads();
      if (kh == 0) {
#pragma unroll
        for (int m = 0; m < 4; ++m) {
#pragma unroll
          for (int r = 0; r < 4; ++r) {
            float v = acc[m][r] + red[ct][m * 4 + r][lane] + x2v[m][r];
            const int sb = (lane & 48) | (lane & 3);
            float vf = __shfl(v, sb, 64);
            float vi = __shfl(v, sb | 4, 64);
            float vo = __shfl(v, sb | 8, 64);
            float vc = __shfl(v, sb | 12, 64);
            float fg = 1.f / (1.f + __expf(-vf));
            float ig = 1.f / (1.f + __expf(-vi));
            float og = 1.f / (1.f + __expf(-vo));
            float e2 = __expf(2.f * vc);
            float ct_ = (e2 - 1.f) / (e2 + 1.f);
            float Cn = fg * Cst[m * 4 + r] + ig * ct_;
            Cst[m * 4 + r] = Cn;
            float e2c = __expf(2.f * Cn);
            float Hn = og * (e2c - 1.f) / (e2c + 1.f);
            if ((lane & 12) == 0) {
              int row = m * 16 + q * 4 + r;
              ast16(&h2all[((size_t)t * 64 + row) * 1024 + h_ew], f2bf(Hn));
              if (t == 255) {
                outF[131072 + row * 1024 + h_ew] = Hn;  // H2 final
                outF[196608 + row * 1024 + h_ew] = Cn;  // C2 final
              }
            }
          }
        }
      }
      publish_slot(g2slots, ms, (unsigned)(t + 1));      // H2(t) published
    }
  } else {
    // ================= GX: X2 precompute (off-chain, full-K waves) =================
    const int ms = bid - 192;                      // 0..63
    const int w = ms * 4 + widx;                   // col-unit 0..255
    const int hcol = w * 4 + (c & 3);
    bf16x8 Breg[32];                               // W2x full-K
    {
      const bf16x8* blob3 = (const bf16x8*)g3blob;
#pragma unroll
      for (int j = 0; j < 32; ++j)
        Breg[j] = blob3[(size_t)(w * 64 + 32 + j) * 64 + lane];
    }
    const float biasv = b2[g * 1024 + hcol];

#pragma clang loop unroll(disable)
    for (int t = 0; t < 256; ++t) {
      wait64(g1slots, (unsigned)(t + 1), poison);       // H1(t) at L3
      if (t >= 4) wait128(g2slots, (unsigned)(t - 3), poison);  // x2 ring backpressure

      stage_H(h1ring + (t & 3) * 65536, Hs);
      __syncthreads();
#pragma unroll
      for (int m = 0; m < 4; ++m) acc[m] = (f32x4){biasv, biasv, biasv, biasv};
#pragma unroll
      for (int j = 0; j < 32; ++j)
#pragma unroll
        for (int m = 0; m < 4; ++m)
          acc[m] = MFMA16x32(lds_frag(Hs, m, j, lane), Breg[j], acc[m]);

      // write X2 (write-through f32): [slot][gate-col fc][batch b]
      float* xp = x2ring + ((size_t)((t & 3) * 4096 + w * 16 + c)) * 64 + q * 4;
#pragma unroll
      for (int m = 0; m < 4; ++m)
#pragma unroll
        for (int r = 0; r < 4; ++r) ast32(&xp[m * 16 + r], acc[m][r]);

      publish_slot(gxslots, ms, (unsigned)(t + 1));     // X2(t) published
    }
  }
}

// ---------------- output projection: Y = H2all @ Wout + bout ----------------
__global__ __launch_bounds__(256, 2) void k_gemm_out(
    const unsigned short* __restrict__ A, const unsigned short* __restrict__ Bt,
    const float* __restrict__ bout, float* __restrict__ C)
{
  __shared__ unsigned short As[128 * 32];
  __shared__ unsigned short Bs[128 * 32];
  const int tid = threadIdx.x, lane = tid & 63, wv = tid >> 6;
  const int c = lane & 15, q = lane >> 4;
  const int bn = blockIdx.x & 31, bm = blockIdx.x >> 5;
  const int wm = wv >> 1, wn = wv & 1;

  f32x4 acc[4][4];
#pragma unroll
  for (int m = 0; m < 4; ++m)
#pragma unroll
    for (int n = 0; n < 4; ++n) acc[m][n] = (f32x4){0.f, 0.f, 0.f, 0.f};

  const unsigned short* Abase = A + (size_t)(bm * 128) * 1024;
  const unsigned short* Bbase = Bt + (size_t)(bn * 128) * 1024;

  for (int kt = 0; kt < 32; ++kt) {
    if (kt) __syncthreads();
#pragma unroll
    for (int ch = 0; ch < 2; ++ch) {
      int o = ch * 4096 + tid * 16;
      int row = o >> 6;
      int ks = (o & 63) >> 1;
      *(bf16x8*)&As[o >> 1] = *(const bf16x8*)(Abase + (size_t)row * 1024 + kt * 32 + ks);
      *(bf16x8*)&Bs[o >> 1] = *(const bf16x8*)(Bbase + (size_t)row * 1024 + kt * 32 + ks);
    }
    __syncthreads();
    bf16x8 af[4], bfr[4];
#pragma unroll
    for (int m = 0; m < 4; ++m) af[m] = *(const bf16x8*)&As[(wm * 64 + m * 16 + c) * 32 + q * 8];
#pragma unroll
    for (int n = 0; n < 4; ++n) bfr[n] = *(const bf16x8*)&Bs[(wn * 64 + n * 16 + c) * 32 + q * 8];
#pragma unroll
    for (int m = 0; m < 4; ++m)
#pragma unroll
      for (int n = 0; n < 4; ++n) acc[m][n] = MFMA16x32(af[m], bfr[n], acc[m][n]);
  }

#pragma unroll
  for (int n = 0; n < 4; ++n) {
    int col = bn * 128 + wn * 64 + n * 16 + c;
    float bo = bout[col];
#pragma unroll
    for (int m = 0; m < 4; ++m) {
      int row0 = bm * 128 + wm * 64 + m * 16 + q * 4;
#pragma unroll
      for (int r = 0; r < 4; ++r)
        C[(size_t)(row0 + r) * 4096 + col] = acc[m][n][r] + bo;
    }
  }
}

extern "C" void kernel_launch(void* const* d_in, const int* in_sizes, int n_in,
                              void* d_out, int out_size, void* d_ws, size_t ws_size,
                              hipStream_t stream) {
  const int* tokens = (const int*)d_in[0];
  const float* W1 = (const float*)d_in[1];
  const float* b1 = (const float*)d_in[2];
  const float* W2 = (const float*)d_in[3];
  const float* b2 = (const float*)d_in[4];
  const float* Wout = (const float*)d_in[5];
  const float* bout = (const float*)d_in[6];

  char* ws = (char*)d_ws;
  unsigned short* g1blob = (unsigned short*)(ws + WS_G1BLOB);
  unsigned short* g3blob = (unsigned short*)(ws + WS_G3BLOB);
  unsigned short* woutT  = (unsigned short*)(ws + WS_WOUTT);
  unsigned short* h1ring = (unsigned short*)(ws + WS_H1RING);
  unsigned*       syncb  = (unsigned*)(ws + WS_SYNC);
  unsigned short* h2all  = (unsigned short*)(ws + WS_H2ALL);
  float*          x2ring = (float*)(ws + WS_X2);

  float* outY = (float*)d_out;
  float* outF = outY + 67108864;   // Y then H1,C1,H2,C2

  hipLaunchKernelGGL(k_init, dim3(16), dim3(256), 0, stream, syncb, 4096);
  hipLaunchKernelGGL(k_pack_g1, dim3(2048), dim3(256), 0, stream, W1, g1blob);
  hipLaunchKernelGGL(k_pack_g3, dim3(4096), dim3(256), 0, stream, W2, g3blob);
  hipLaunchKernelGGL(k_pack_woutT, dim3(16384), dim3(256), 0, stream, Wout, woutT);

  hipLaunchKernelGGL(k_lstm, dim3(256), dim3(256), 0, stream,
                     tokens, W1, b1, b2, g1blob, g3blob, h1ring, h2all,
                     x2ring, outF, syncb);

  hipLaunchKernelGGL(k_gemm_out, dim3(4096), dim3(256), 0, stream, h2all, woutT, bout, outY);
}

// Round 14
// 3950.187 us; speedup vs baseline: 1.3197x; 1.1742x over previous
//
#include <hip/hip_runtime.h>
#include <hip/hip_bf16.h>

typedef float f32x4 __attribute__((ext_vector_type(4)));
typedef short bf16x8 __attribute__((ext_vector_type(8)));

#define MFMA16x32(a,b,c) __builtin_amdgcn_mfma_f32_16x16x32_bf16((a),(b),(c),0,0,0)

__device__ __forceinline__ unsigned short f2bf(float f) {
  unsigned u = __float_as_uint(f);
  u += 0x7fffu + ((u >> 16) & 1u);
  return (unsigned short)(u >> 16);
}

// Write-through relaxed agent stores (bypass L2 -> L3-visible after vmcnt ack). R6-R13.
__device__ __forceinline__ void ast16(unsigned short* p, unsigned short v) {
  __hip_atomic_store(p, v, __ATOMIC_RELAXED, __HIP_MEMORY_SCOPE_AGENT);
}

// L1/L2-bypass 16B load (reads the L3 coherence point; pipelined).
__device__ __forceinline__ bf16x8 ld16bf(const void* p) {
  bf16x8 r;
  asm volatile("global_load_dwordx4 %0, %1, off sc0 sc1" : "=v"(r) : "v"(p) : "memory");
  return r;
}

// ---------------- workspace layout (bytes) ----------------
#define WS_G1BLOB 0ull
#define WS_G3BLOB 8388608ull
#define WS_WOUTT  25165824ull
#define WS_H1RING 33554432ull
#define WS_SYNC   34078720ull
#define WS_H2ALL  34095104ull

#define SLSTRIDE 8   // u32 per sync slot (32B per block; 128 slots/group = 4KB)

__global__ void k_init(unsigned* __restrict__ p, int n) {
  int i = blockIdx.x * blockDim.x + threadIdx.x;
  for (; i < n; i += gridDim.x * blockDim.x) p[i] = 0u;
}

// ---------------- pack W1h into per-wave B-fragment blob ----------------
__global__ void k_pack_g1(const float* __restrict__ W1, unsigned short* __restrict__ blob) {
  int gtid = blockIdx.x * 256 + threadIdx.x;      // 524288 threads
  int lane = gtid & 63, kk = (gtid >> 6) & 31, w = gtid >> 11;
  int c = lane & 15, q = lane >> 4;
  int g = c >> 2, h = w * 4 + (c & 3);
  bf16x8 s;
#pragma unroll
  for (int j = 0; j < 8; ++j) {
    int k = kk * 32 + q * 8 + j;
    float v = W1[(size_t)g * 5242880u + (size_t)(4096 + k) * 1024u + h];
    ((unsigned short*)&s)[j] = f2bf(v);
  }
  ((bf16x8*)blob)[(size_t)(w * 32 + kk) * 64 + lane] = s;
}

// ---------------- pack W2 (kk<32 -> W2h rows 1024+, kk>=32 -> W2x rows 0..1023) ----------------
__global__ void k_pack_g3(const float* __restrict__ W2, unsigned short* __restrict__ blob) {
  int gtid = blockIdx.x * 256 + threadIdx.x;      // 1048576 threads
  int lane = gtid & 63, kk = (gtid >> 6) & 63, w = gtid >> 12;
  int c = lane & 15, q = lane >> 4;
  int g = c >> 2, h = w * 4 + (c & 3);
  bf16x8 s;
#pragma unroll
  for (int j = 0; j < 8; ++j) {
    int klocal = (kk & 31) * 32 + q * 8 + j;
    int d = (kk < 32) ? (1024 + klocal) : klocal;
    float v = W2[(size_t)g * 2097152u + (size_t)d * 1024u + h];
    ((unsigned short*)&s)[j] = f2bf(v);
  }
  ((bf16x8*)blob)[(size_t)(w * 64 + kk) * 64 + lane] = s;
}

// ---------------- Wout^T bf16 ----------------
__global__ void k_pack_woutT(const float* __restrict__ Wout, unsigned short* __restrict__ wT) {
  int gtid = blockIdx.x * 256 + threadIdx.x;      // 4,194,304 threads
  int k = gtid & 1023, n = gtid >> 10;
  wT[(size_t)n * 1024 + k] = f2bf(Wout[(size_t)k * 4096 + n]);
}

// ---------------- flag-array sync over 128 slots (fence-free, proven) ----------------
__device__ __forceinline__ void wait_slots(const unsigned* __restrict__ slots,
                                           unsigned epoch, unsigned* __restrict__ poison) {
  if (threadIdx.x < 64) {
    unsigned guard = 0;
    for (;;) {
      unsigned v0 = __hip_atomic_load(&slots[threadIdx.x * SLSTRIDE],
                                      __ATOMIC_RELAXED, __HIP_MEMORY_SCOPE_AGENT);
      unsigned v1 = __hip_atomic_load(&slots[(threadIdx.x + 64) * SLSTRIDE],
                                      __ATOMIC_RELAXED, __HIP_MEMORY_SCOPE_AGENT);
      unsigned v = v0 < v1 ? v0 : v1;
      if (__all((int)(v >= epoch))) break;
      __builtin_amdgcn_s_sleep(1);
      if (((++guard) & 1023u) == 0u) {
        if (guard > (1u << 18) ||
            __hip_atomic_load(poison, __ATOMIC_RELAXED, __HIP_MEMORY_SCOPE_AGENT) != 0u) {
          __hip_atomic_store(poison, 1u, __ATOMIC_RELAXED, __HIP_MEMORY_SCOPE_AGENT);
          break;   // fail-visible, never hard-hang
        }
      }
    }
  }
  __syncthreads();
}

// Publish: drain write-through stores (=> visible at L3), block barrier, flag store.
__device__ __forceinline__ void publish_slot(unsigned* __restrict__ slots,
                                             int myslot, unsigned epoch) {
  asm volatile("s_waitcnt vmcnt(0)" ::: "memory");
  __syncthreads();
  if (threadIdx.x == 0) {
    __hip_atomic_store(&slots[myslot * SLSTRIDE], epoch,
                       __ATOMIC_RELAXED, __HIP_MEMORY_SCOPE_AGENT);
  }
}

// ---------------- stage 128KB H global->LDS in FRAGMENT ORDER (R13-proven, 0 conflicts) ----
// Wave widx stages fragment-blocks (m=widx, kk=it): lane loads global 16B at
// row (widx*16+c), k-bytes it*64+q*16; writes LDS at ((it*4+widx)*64+lane)*16.
// Both ds_write and later ds_read_b128 are lane-sequential: ZERO bank conflicts.
__device__ __forceinline__ void stage_H(const unsigned short* __restrict__ Hsrc,
                                        unsigned short* __restrict__ Hs) {
  asm volatile("s_waitcnt vmcnt(0)" ::: "memory");   // isolate counted window
  const int lane = threadIdx.x & 63, widx = threadIdx.x >> 6;
  const int c = lane & 15, q = lane >> 4;
  const char* src = (const char*)Hsrc + (widx * 16 + c) * 2048 + q * 16;
  char* dst = (char*)Hs + widx * 1024 + lane * 16;
  bf16x8 v[2][8];
#define ISS(BUF, IT0) \
  _Pragma("unroll") for (int i = 0; i < 8; ++i) v[BUF][i] = ld16bf(src + ((IT0) + i) * 64);
#define WRB(BUF, IT0) \
  _Pragma("unroll") for (int i = 0; i < 8; ++i) *(bf16x8*)(dst + ((IT0) + i) * 4096) = v[BUF][i];
#define W8 asm volatile("s_waitcnt vmcnt(8)" ::: "memory"); __builtin_amdgcn_sched_barrier(0);
#define W0 asm volatile("s_waitcnt vmcnt(0)" ::: "memory"); __builtin_amdgcn_sched_barrier(0);
  ISS(0, 0) ISS(1, 8)
  W8 WRB(0, 0) ISS(0, 16)
  W8 WRB(1, 8) ISS(1, 24)
  W8 WRB(0, 16)
  W0 WRB(1, 24)
#undef ISS
#undef WRB
#undef W8
#undef W0
}

// fragment read: (m, kk) -> bf16x8 at lane-sequential address (conflict-free)
__device__ __forceinline__ bf16x8 lds_frag(const unsigned short* __restrict__ Hs,
                                           int m, int kk, int lane) {
  return *(const bf16x8*)((const char*)Hs + ((kk * 4 + m) * 64 + lane) * 16);
}

// ---------------- persistent recurrent kernel: 256 blocks, K-split pairs (R11 flow) ----------
// G1 (blocks 0..127):   H1(t) -> h1ring[t&3].  Block covers 32 cols (2 tiles).
// G3 (blocks 128..255): H2(t) -> h2all[t]. Phase C (H1(t)@W2x) hoisted PRE-barrier.
// wave widx -> col-tile ct=widx>>1, K-half kh=widx&1.
__global__ __launch_bounds__(256, 1) void k_lstm(
    const int* __restrict__ tokens, const float* __restrict__ W1,
    const float* __restrict__ b1, const float* __restrict__ b2,
    const unsigned short* __restrict__ g1blob, const unsigned short* __restrict__ g3blob,
    unsigned short* __restrict__ h1ring, unsigned short* __restrict__ h2all,
    float* __restrict__ outF, unsigned* __restrict__ syncbase)
{
  __shared__ unsigned short Hs[65536];   // 128 KB fragment-ordered staging
  __shared__ float red[2][16][64];       // 8 KB lane-major reduce (conflict-free)

  const int tid = threadIdx.x, lane = tid & 63, widx = tid >> 6, bid = blockIdx.x;
  const int c = lane & 15, q = lane >> 4;
  const bool isG1 = bid < 128;
  const int myslot = isG1 ? bid : bid - 128;          // 0..127
  const int ct = widx >> 1, kh = widx & 1;
  const int w = myslot * 2 + ct;                      // 0..255 col-unit (16 cols)
  const int g = c >> 2;
  const int hcol = w * 4 + (c & 3);
  const int h_ew = w * 4 + (lane & 3);

  unsigned* g1slots = syncbase;                       // 128 x 8 u32 (4KB)
  unsigned* g3slots = syncbase + 1024;
  unsigned* poison  = syncbase + 2048;

  // --- preload weight fragments (this wave's K-half only) ---
  bf16x8 Breg[32];
  {
    const bf16x8* blob1 = (const bf16x8*)g1blob;
    const bf16x8* blob3 = (const bf16x8*)g3blob;
    if (isG1) {
#pragma unroll
      for (int j = 0; j < 16; ++j)
        Breg[j] = blob1[(size_t)(w * 32 + kh * 16 + j) * 64 + lane];
    } else {
#pragma unroll
      for (int j = 0; j < 16; ++j) {
        Breg[j]      = blob3[(size_t)(w * 64 + kh * 16 + j) * 64 + lane];        // W2h (phase A)
        Breg[16 + j] = blob3[(size_t)(w * 64 + 32 + kh * 16 + j) * 64 + lane];   // W2x (phase C)
      }
    }
  }
  const float biasv = isG1 ? b1[g * 1024 + hcol] : b2[g * 1024 + hcol];

  float Cst[16];
#pragma unroll
  for (int i = 0; i < 16; ++i) Cst[i] = 0.f;

  // --- G1 kh==0: preload embedding gathers for t=0 ---
  float gv[16];
  if (isG1 && kh == 0) {
#pragma unroll
    for (int m = 0; m < 4; ++m)
#pragma unroll
      for (int r = 0; r < 4; ++r) {
        int b_ = m * 16 + q * 4 + r;
        int tk = tokens[b_ * 256];
        gv[m * 4 + r] = W1[(size_t)g * 5242880u + (size_t)tk * 1024u + hcol];
      }
  }

  f32x4 acc[4];

  if (isG1) {
    // ================= G1 chain =================
#pragma clang loop unroll(disable)
    for (int t = 0; t < 256; ++t) {
      if (t > 0) wait_slots(g1slots, (unsigned)t, poison);   // all H1(t-1) at L3

      int tk2[16];
      if (kh == 0) {
        const int tn = (t < 255) ? t + 1 : 255;
#pragma unroll
        for (int m = 0; m < 4; ++m)
#pragma unroll
          for (int r = 0; r < 4; ++r)
            tk2[m * 4 + r] = tokens[(m * 16 + q * 4 + r) * 256 + tn];
      }

#pragma unroll
      for (int m = 0; m < 4; ++m) acc[m] = (f32x4){0.f, 0.f, 0.f, 0.f};
      if (t > 0) {
        stage_H(h1ring + ((t - 1) & 3) * 65536, Hs);
        __syncthreads();
#pragma unroll
        for (int j = 0; j < 16; ++j)
#pragma unroll
          for (int m = 0; m < 4; ++m)
            acc[m] = MFMA16x32(lds_frag(Hs, m, kh * 16 + j, lane), Breg[j], acc[m]);
      }
      if (t >= 4) wait_slots(g3slots, (unsigned)(t - 3), poison);  // ring backpressure
      else __syncthreads();   // Hs reads done before next stage (uniform barrier)

      // K-split partial exchange (lane-major, conflict-free)
      if (kh == 1) {
#pragma unroll
        for (int m = 0; m < 4; ++m)
#pragma unroll
          for (int r = 0; r < 4; ++r) red[ct][m * 4 + r][lane] = acc[m][r];
      }
      __syncthreads();
      if (kh == 0) {
#pragma unroll
        for (int m = 0; m < 4; ++m) {
#pragma unroll
          for (int r = 0; r < 4; ++r) {
            float v = acc[m][r] + red[ct][m * 4 + r][lane] + gv[m * 4 + r] + biasv;
            const int sb = (lane & 48) | (lane & 3);
            float vf = __shfl(v, sb, 64);
            float vi = __shfl(v, sb | 4, 64);
            float vo = __shfl(v, sb | 8, 64);
            float vc = __shfl(v, sb | 12, 64);
            float fg = 1.f / (1.f + __expf(-vf));
            float ig = 1.f / (1.f + __expf(-vi));
            float og = 1.f / (1.f + __expf(-vo));
            float e2 = __expf(2.f * vc);
            float ct_ = (e2 - 1.f) / (e2 + 1.f);
            float Cn = fg * Cst[m * 4 + r] + ig * ct_;
            Cst[m * 4 + r] = Cn;
            float e2c = __expf(2.f * Cn);
            float Hn = og * (e2c - 1.f) / (e2c + 1.f);
            if ((lane & 12) == 0) {
              int row = m * 16 + q * 4 + r;
              ast16(&h1ring[(t & 3) * 65536 + row * 1024 + h_ew], f2bf(Hn));
              if (t == 255) {
                outF[row * 1024 + h_ew] = Hn;           // H1 final
                outF[65536 + row * 1024 + h_ew] = Cn;   // C1 final
              }
            }
          }
        }
      }
      publish_slot(g1slots, myslot, (unsigned)(t + 1));      // H1(t) published

      // prefetch next step's embedding gathers (latency hides under next poll)
      if (kh == 0) {
#pragma unroll
        for (int i = 0; i < 16; ++i)
          gv[i] = W1[(size_t)g * 5242880u + (size_t)tk2[i] * 1024u + hcol];
      }
    }
  } else {
    // ================= G3 chain =================
#pragma clang loop unroll(disable)
    for (int t = 0; t < 256; ++t) {
      // phase C FIRST (early start): H1(t) available since G1 runs ahead;
      // overlaps peers still finishing step t-1.
      wait_slots(g1slots, (unsigned)(t + 1), poison);
#pragma unroll
      for (int m = 0; m < 4; ++m)
        acc[m] = (kh == 0) ? (f32x4){biasv, biasv, biasv, biasv}
                           : (f32x4){0.f, 0.f, 0.f, 0.f};
      stage_H(h1ring + (t & 3) * 65536, Hs);
      __syncthreads();
#pragma unroll
      for (int j = 0; j < 16; ++j)
#pragma unroll
        for (int m = 0; m < 4; ++m)
          acc[m] = MFMA16x32(lds_frag(Hs, m, kh * 16 + j, lane), Breg[16 + j], acc[m]);
      __syncthreads();   // Hs reads done before phase-A staging

      if (t > 0) {       // phase A: H2(t-1) @ W2h (own-group barrier)
        wait_slots(g3slots, (unsigned)t, poison);
        stage_H(h2all + (size_t)(t - 1) * 65536, Hs);
        __syncthreads();
#pragma unroll
        for (int j = 0; j < 16; ++j)
#pragma unroll
          for (int m = 0; m < 4; ++m)
            acc[m] = MFMA16x32(lds_frag(Hs, m, kh * 16 + j, lane), Breg[j], acc[m]);
      }

      // K-split partial exchange (lane-major, conflict-free)
      if (kh == 1) {
#pragma unroll
        for (int m = 0; m < 4; ++m)
#pragma unroll
          for (int r = 0; r < 4; ++r) red[ct][m * 4 + r][lane] = acc[m][r];
      }
      __syncthreads();
      if (kh == 0) {
#pragma unroll
        for (int m = 0; m < 4; ++m) {
#pragma unroll
          for (int r = 0; r < 4; ++r) {
            float v = acc[m][r] + red[ct][m * 4 + r][lane];
            const int sb = (lane & 48) | (lane & 3);
            float vf = __shfl(v, sb, 64);
            float vi = __shfl(v, sb | 4, 64);
            float vo = __shfl(v, sb | 8, 64);
            float vc = __shfl(v, sb | 12, 64);
            float fg = 1.f / (1.f + __expf(-vf));
            float ig = 1.f / (1.f + __expf(-vi));
            float og = 1.f / (1.f + __expf(-vo));
            float e2 = __expf(2.f * vc);
            float ct_ = (e2 - 1.f) / (e2 + 1.f);
            float Cn = fg * Cst[m * 4 + r] + ig * ct_;
            Cst[m * 4 + r] = Cn;
            float e2c = __expf(2.f * Cn);
            float Hn = og * (e2c - 1.f) / (e2c + 1.f);
            if ((lane & 12) == 0) {
              int row = m * 16 + q * 4 + r;
              ast16(&h2all[((size_t)t * 64 + row) * 1024 + h_ew], f2bf(Hn));
              if (t == 255) {
                outF[131072 + row * 1024 + h_ew] = Hn;  // H2 final
                outF[196608 + row * 1024 + h_ew] = Cn;  // C2 final
              }
            }
          }
        }
      }
      publish_slot(g3slots, myslot, (unsigned)(t + 1));      // H2(t) published
    }
  }
}

// ---------------- output projection: Y = H2all @ Wout + bout ----------------
__global__ __launch_bounds__(256, 2) void k_gemm_out(
    const unsigned short* __restrict__ A, const unsigned short* __restrict__ Bt,
    const float* __restrict__ bout, float* __restrict__ C)
{
  __shared__ unsigned short As[128 * 32];
  __shared__ unsigned short Bs[128 * 32];
  const int tid = threadIdx.x, lane = tid & 63, wv = tid >> 6;
  const int c = lane & 15, q = lane >> 4;
  const int bn = blockIdx.x & 31, bm = blockIdx.x >> 5;
  const int wm = wv >> 1, wn = wv & 1;

  f32x4 acc[4][4];
#pragma unroll
  for (int m = 0; m < 4; ++m)
#pragma unroll
    for (int n = 0; n < 4; ++n) acc[m][n] = (f32x4){0.f, 0.f, 0.f, 0.f};

  const unsigned short* Abase = A + (size_t)(bm * 128) * 1024;
  const unsigned short* Bbase = Bt + (size_t)(bn * 128) * 1024;

  for (int kt = 0; kt < 32; ++kt) {
    if (kt) __syncthreads();
#pragma unroll
    for (int ch = 0; ch < 2; ++ch) {
      int o = ch * 4096 + tid * 16;
      int row = o >> 6;
      int ks = (o & 63) >> 1;
      *(bf16x8*)&As[o >> 1] = *(const bf16x8*)(Abase + (size_t)row * 1024 + kt * 32 + ks);
      *(bf16x8*)&Bs[o >> 1] = *(const bf16x8*)(Bbase + (size_t)row * 1024 + kt * 32 + ks);
    }
    __syncthreads();
    bf16x8 af[4], bfr[4];
#pragma unroll
    for (int m = 0; m < 4; ++m) af[m] = *(const bf16x8*)&As[(wm * 64 + m * 16 + c) * 32 + q * 8];
#pragma unroll
    for (int n = 0; n < 4; ++n) bfr[n] = *(const bf16x8*)&Bs[(wn * 64 + n * 16 + c) * 32 + q * 8];
#pragma unroll
    for (int m = 0; m < 4; ++m)
#pragma unroll
      for (int n = 0; n < 4; ++n) acc[m][n] = MFMA16x32(af[m], bfr[n], acc[m][n]);
  }

#pragma unroll
  for (int n = 0; n < 4; ++n) {
    int col = bn * 128 + wn * 64 + n * 16 + c;
    float bo = bout[col];
#pragma unroll
    for (int m = 0; m < 4; ++m) {
      int row0 = bm * 128 + wm * 64 + m * 16 + q * 4;
#pragma unroll
      for (int r = 0; r < 4; ++r)
        C[(size_t)(row0 + r) * 4096 + col] = acc[m][n][r] + bo;
    }
  }
}

extern "C" void kernel_launch(void* const* d_in, const int* in_sizes, int n_in,
                              void* d_out, int out_size, void* d_ws, size_t ws_size,
                              hipStream_t stream) {
  const int* tokens = (const int*)d_in[0];
  const float* W1 = (const float*)d_in[1];
  const float* b1 = (const float*)d_in[2];
  const float* W2 = (const float*)d_in[3];
  const float* b2 = (const float*)d_in[4];
  const float* Wout = (const float*)d_in[5];
  const float* bout = (const float*)d_in[6];

  char* ws = (char*)d_ws;
  unsigned short* g1blob = (unsigned short*)(ws + WS_G1BLOB);
  unsigned short* g3blob = (unsigned short*)(ws + WS_G3BLOB);
  unsigned short* woutT  = (unsigned short*)(ws + WS_WOUTT);
  unsigned short* h1ring = (unsigned short*)(ws + WS_H1RING);
  unsigned*       syncb  = (unsigned*)(ws + WS_SYNC);
  unsigned short* h2all  = (unsigned short*)(ws + WS_H2ALL);

  float* outY = (float*)d_out;
  float* outF = outY + 67108864;   // Y then H1,C1,H2,C2

  hipLaunchKernelGGL(k_init, dim3(16), dim3(256), 0, stream, syncb, 4096);
  hipLaunchKernelGGL(k_pack_g1, dim3(2048), dim3(256), 0, stream, W1, g1blob);
  hipLaunchKernelGGL(k_pack_g3, dim3(4096), dim3(256), 0, stream, W2, g3blob);
  hipLaunchKernelGGL(k_pack_woutT, dim3(16384), dim3(256), 0, stream, Wout, woutT);

  hipLaunchKernelGGL(k_lstm, dim3(256), dim3(256), 0, stream,
                     tokens, W1, b1, b2, g1blob, g3blob, h1ring, h2all, outF, syncb);

  hipLaunchKernelGGL(k_gemm_out, dim3(4096), dim3(256), 0, stream, h2all, woutT, bout, outY);
}

// Round 15
// 2766.912 us; speedup vs baseline: 1.8841x; 1.4277x over previous
//
#include <hip/hip_runtime.h>
#include <hip/hip_bf16.h>

typedef float f32x4 __attribute__((ext_vector_type(4)));
typedef short bf16x8 __attribute__((ext_vector_type(8)));
typedef unsigned int u32x4 __attribute__((ext_vector_type(4)));

#define MFMA16x32(a,b,c) __builtin_amdgcn_mfma_f32_16x16x32_bf16((a),(b),(c),0,0,0)

__device__ __forceinline__ unsigned short f2bf(float f) {
  unsigned u = __float_as_uint(f);
  u += 0x7fffu + ((u >> 16) & 1u);
  return (unsigned short)(u >> 16);
}

// H stores: relaxed agent-scope = write-through past L2 into L3 (no dirty L2
// lines). vmcnt(0) ack => globally visible. Proven R6-R14.
__device__ __forceinline__ void ast16(unsigned short* p, unsigned short v) {
  __hip_atomic_store(p, v, __ATOMIC_RELAXED, __HIP_MEMORY_SCOPE_AGENT);
}

// L1/L2-bypass 16B load (reads the L3 coherence point; pipelined).
__device__ __forceinline__ u32x4 ld16_bypass(const void* p) {
  u32x4 r;
  asm volatile("global_load_dwordx4 %0, %1, off sc0 sc1" : "=v"(r) : "v"(p) : "memory");
  return r;
}

// ---------------- workspace layout (bytes) ----------------
#define WS_G1BLOB 0ull
#define WS_G3BLOB 8388608ull
#define WS_WOUTT  25165824ull
#define WS_H1RING 33554432ull
#define WS_SYNC   34078720ull
#define WS_H2ALL  34095104ull

#define SLSTRIDE 8   // u32 per sync slot (32B per block; 128 slots/group = 4KB)

__global__ void k_init(unsigned* __restrict__ p, int n) {
  int i = blockIdx.x * blockDim.x + threadIdx.x;
  for (; i < n; i += gridDim.x * blockDim.x) p[i] = 0u;
}

// ---------------- pack W1h into per-wave B-fragment blob ----------------
__global__ void k_pack_g1(const float* __restrict__ W1, unsigned short* __restrict__ blob) {
  int gtid = blockIdx.x * 256 + threadIdx.x;      // 524288 threads
  int lane = gtid & 63, kk = (gtid >> 6) & 31, w = gtid >> 11;
  int c = lane & 15, q = lane >> 4;
  int g = c >> 2, h = w * 4 + (c & 3);
  bf16x8 s;
#pragma unroll
  for (int j = 0; j < 8; ++j) {
    int k = kk * 32 + q * 8 + j;
    float v = W1[(size_t)g * 5242880u + (size_t)(4096 + k) * 1024u + h];
    ((unsigned short*)&s)[j] = f2bf(v);
  }
  ((bf16x8*)blob)[(size_t)(w * 32 + kk) * 64 + lane] = s;
}

// ---------------- pack W2 (kk<32 -> W2h rows 1024+, kk>=32 -> W2x rows 0..1023) ----------------
__global__ void k_pack_g3(const float* __restrict__ W2, unsigned short* __restrict__ blob) {
  int gtid = blockIdx.x * 256 + threadIdx.x;      // 1048576 threads
  int lane = gtid & 63, kk = (gtid >> 6) & 63, w = gtid >> 12;
  int c = lane & 15, q = lane >> 4;
  int g = c >> 2, h = w * 4 + (c & 3);
  bf16x8 s;
#pragma unroll
  for (int j = 0; j < 8; ++j) {
    int klocal = (kk & 31) * 32 + q * 8 + j;
    int d = (kk < 32) ? (1024 + klocal) : klocal;
    float v = W2[(size_t)g * 2097152u + (size_t)d * 1024u + h];
    ((unsigned short*)&s)[j] = f2bf(v);
  }
  ((bf16x8*)blob)[(size_t)(w * 64 + kk) * 64 + lane] = s;
}

// ---------------- Wout^T bf16 ----------------
__global__ void k_pack_woutT(const float* __restrict__ Wout, unsigned short* __restrict__ wT) {
  int gtid = blockIdx.x * 256 + threadIdx.x;      // 4,194,304 threads
  int k = gtid & 1023, n = gtid >> 10;
  wT[(size_t)n * 1024 + k] = f2bf(Wout[(size_t)k * 4096 + n]);
}

// ---------------- flag-array sync over 128 slots (fence-free) ----------------
__device__ __forceinline__ void wait_slots(const unsigned* __restrict__ slots,
                                           unsigned epoch, unsigned* __restrict__ poison) {
  if (threadIdx.x < 64) {
    unsigned guard = 0;
    for (;;) {
      unsigned v0 = __hip_atomic_load(&slots[threadIdx.x * SLSTRIDE],
                                      __ATOMIC_RELAXED, __HIP_MEMORY_SCOPE_AGENT);
      unsigned v1 = __hip_atomic_load(&slots[(threadIdx.x + 64) * SLSTRIDE],
                                      __ATOMIC_RELAXED, __HIP_MEMORY_SCOPE_AGENT);
      unsigned v = v0 < v1 ? v0 : v1;
      if (__all((int)(v >= epoch))) break;
      __builtin_amdgcn_s_sleep(1);
      if (((++guard) & 1023u) == 0u) {
        if (guard > (1u << 18) ||
            __hip_atomic_load(poison, __ATOMIC_RELAXED, __HIP_MEMORY_SCOPE_AGENT) != 0u) {
          __hip_atomic_store(poison, 1u, __ATOMIC_RELAXED, __HIP_MEMORY_SCOPE_AGENT);
          break;   // fail-visible, never hard-hang
        }
      }
    }
  }
  __syncthreads();
}

// Publish: drain write-through stores (=> visible at L3), block barrier, flag store.
__device__ __forceinline__ void publish_slot(unsigned* __restrict__ slots,
                                             int myslot, unsigned epoch) {
  asm volatile("s_waitcnt vmcnt(0)" ::: "memory");
  __syncthreads();
  if (threadIdx.x == 0) {
    __hip_atomic_store(&slots[myslot * SLSTRIDE], epoch,
                       __ATOMIC_RELAXED, __HIP_MEMORY_SCOPE_AGENT);
  }
}

// ---------------- stage 128KB H matrix global->LDS: pipelined bypass loads ----
// CONTIGUOUS global reads (swizzle folded into source, permutes only within a
// 2KB row -> fully coalesced); linear LDS writes. R11-proven.
// LDS byte P holds H[row][ (P&2047) ^ ((row&7)<<4) ], row = P>>11.
__device__ __forceinline__ void stage_H(const unsigned short* __restrict__ Hsrc,
                                        unsigned short* __restrict__ Hs) {
  asm volatile("s_waitcnt vmcnt(0)" ::: "memory");   // isolate counted window
  const int tid = threadIdx.x;
  const char* base = (const char*)Hsrc;
  const int rowlo = tid >> 7;
  const int x = (tid & 127) * 16;
  u32x4 v[4][8];
#define ISSUE_BATCH(B) \
  _Pragma("unroll") \
  for (int r8 = 0; r8 < 8; ++r8) { \
    int row = ((B) * 8 + r8) * 2 + rowlo; \
    v[B][r8] = ld16_bypass(base + row * 2048 + (x ^ ((row & 7) << 4))); \
  }
#define WRITE_BATCH(B) \
  _Pragma("unroll") \
  for (int r8 = 0; r8 < 8; ++r8) \
    *(u32x4*)((char*)Hs + ((B) * 8 + r8) * 4096 + tid * 16) = v[B][r8];

  ISSUE_BATCH(0)
  ISSUE_BATCH(1)
  asm volatile("s_waitcnt vmcnt(8)" ::: "memory");
  __builtin_amdgcn_sched_barrier(0);
  WRITE_BATCH(0)
  ISSUE_BATCH(2)
  asm volatile("s_waitcnt vmcnt(8)" ::: "memory");
  __builtin_amdgcn_sched_barrier(0);
  WRITE_BATCH(1)
  ISSUE_BATCH(3)
  asm volatile("s_waitcnt vmcnt(8)" ::: "memory");
  __builtin_amdgcn_sched_barrier(0);
  WRITE_BATCH(2)
  asm volatile("s_waitcnt vmcnt(0)" ::: "memory");
  __builtin_amdgcn_sched_barrier(0);
  WRITE_BATCH(3)
#undef ISSUE_BATCH
#undef WRITE_BATCH
}

// swizzled LDS fragment read: row, colb(bytes) -> bf16x8 (ds_read_b128)
__device__ __forceinline__ bf16x8 lds_frag(const unsigned short* __restrict__ Hs,
                                           int row, int colb) {
  return *(const bf16x8*)((const char*)Hs + row * 2048 + (colb ^ ((row & 7) << 4)));
}

// ---------------- persistent recurrent kernel: 256 blocks, K-split pairs (R11 flow) ----------
// G1 (blocks 0..127):   H1(t) -> h1ring[t&3].  Block covers 32 cols (2 tiles).
// G3 (blocks 128..255): H2(t) -> h2all[t]. Phase C (H1(t)@W2x) hoisted PRE-barrier.
// wave widx -> col-tile ct=widx>>1, K-half kh=widx&1.
// ONLY change vs R11: reduce buffer is lane-major [2][16][64] (bank = lane, no conflicts).
__global__ __launch_bounds__(256, 1) void k_lstm(
    const int* __restrict__ tokens, const float* __restrict__ W1,
    const float* __restrict__ b1, const float* __restrict__ b2,
    const unsigned short* __restrict__ g1blob, const unsigned short* __restrict__ g3blob,
    unsigned short* __restrict__ h1ring, unsigned short* __restrict__ h2all,
    float* __restrict__ outF, unsigned* __restrict__ syncbase)
{
  __shared__ unsigned short Hs[65536];   // 128 KB staging buffer
  __shared__ float red[2][16][64];       // 8 KB lane-major K-split exchange (conflict-free)

  const int tid = threadIdx.x, lane = tid & 63, widx = tid >> 6, bid = blockIdx.x;
  const int c = lane & 15, q = lane >> 4;
  const bool isG1 = bid < 128;
  const int myslot = isG1 ? bid : bid - 128;          // 0..127
  const int ct = widx >> 1, kh = widx & 1;
  const int w = myslot * 2 + ct;                      // 0..255 col-unit (16 cols)
  const int g = c >> 2;
  const int hcol = w * 4 + (c & 3);
  const int h_ew = w * 4 + (lane & 3);

  unsigned* g1slots = syncbase;                       // 128 x 8 u32 (4KB)
  unsigned* g3slots = syncbase + 1024;
  unsigned* poison  = syncbase + 2048;

  // --- preload weight fragments (this wave's K-half only) ---
  bf16x8 Breg[32];
  {
    const bf16x8* blob1 = (const bf16x8*)g1blob;
    const bf16x8* blob3 = (const bf16x8*)g3blob;
    if (isG1) {
#pragma unroll
      for (int j = 0; j < 16; ++j)
        Breg[j] = blob1[(size_t)(w * 32 + kh * 16 + j) * 64 + lane];
    } else {
#pragma unroll
      for (int j = 0; j < 16; ++j) {
        Breg[j]      = blob3[(size_t)(w * 64 + kh * 16 + j) * 64 + lane];        // W2h (phase A)
        Breg[16 + j] = blob3[(size_t)(w * 64 + 32 + kh * 16 + j) * 64 + lane];   // W2x (phase C)
      }
    }
  }
  const float biasv = isG1 ? b1[g * 1024 + hcol] : b2[g * 1024 + hcol];

  float Cst[16];
#pragma unroll
  for (int i = 0; i < 16; ++i) Cst[i] = 0.f;

  // --- G1 kh==0: preload embedding gathers for t=0 ---
  float gv[16];
  if (isG1 && kh == 0) {
#pragma unroll
    for (int m = 0; m < 4; ++m)
#pragma unroll
      for (int r = 0; r < 4; ++r) {
        int b_ = m * 16 + q * 4 + r;
        int tk = tokens[b_ * 256];
        gv[m * 4 + r] = W1[(size_t)g * 5242880u + (size_t)tk * 1024u + hcol];
      }
  }

  f32x4 acc[4];

  if (isG1) {
    // ================= G1 chain =================
#pragma clang loop unroll(disable)
    for (int t = 0; t < 256; ++t) {
      if (t > 0) wait_slots(g1slots, (unsigned)t, poison);   // all H1(t-1) at L3

      int tk2[16];
      if (kh == 0) {
        const int tn = (t < 255) ? t + 1 : 255;
#pragma unroll
        for (int m = 0; m < 4; ++m)
#pragma unroll
          for (int r = 0; r < 4; ++r)
            tk2[m * 4 + r] = tokens[(m * 16 + q * 4 + r) * 256 + tn];
      }

#pragma unroll
      for (int m = 0; m < 4; ++m) acc[m] = (f32x4){0.f, 0.f, 0.f, 0.f};
      if (t > 0) {
        stage_H(h1ring + ((t - 1) & 3) * 65536, Hs);
        __syncthreads();
#pragma unroll
        for (int j = 0; j < 16; ++j)
#pragma unroll
          for (int m = 0; m < 4; ++m)
            acc[m] = MFMA16x32(lds_frag(Hs, m * 16 + c, (kh * 16 + j) * 64 + q * 16),
                               Breg[j], acc[m]);
      }
      if (t >= 4) wait_slots(g3slots, (unsigned)(t - 3), poison);  // ring backpressure
      else __syncthreads();   // Hs reads done before next stage (uniform barrier)

      // K-split partial exchange (lane-major, conflict-free)
      if (kh == 1) {
#pragma unroll
        for (int m = 0; m < 4; ++m)
#pragma unroll
          for (int r = 0; r < 4; ++r) red[ct][m * 4 + r][lane] = acc[m][r];
      }
      __syncthreads();
      if (kh == 0) {
#pragma unroll
        for (int m = 0; m < 4; ++m) {
#pragma unroll
          for (int r = 0; r < 4; ++r) {
            float v = acc[m][r] + red[ct][m * 4 + r][lane] + gv[m * 4 + r] + biasv;
            const int sb = (lane & 48) | (lane & 3);
            float vf = __shfl(v, sb, 64);
            float vi = __shfl(v, sb | 4, 64);
            float vo = __shfl(v, sb | 8, 64);
            float vc = __shfl(v, sb | 12, 64);
            float fg = 1.f / (1.f + __expf(-vf));
            float ig = 1.f / (1.f + __expf(-vi));
            float og = 1.f / (1.f + __expf(-vo));
            float e2 = __expf(2.f * vc);
            float ct_ = (e2 - 1.f) / (e2 + 1.f);
            float Cn = fg * Cst[m * 4 + r] + ig * ct_;
            Cst[m * 4 + r] = Cn;
            float e2c = __expf(2.f * Cn);
            float Hn = og * (e2c - 1.f) / (e2c + 1.f);
            if ((lane & 12) == 0) {
              int row = m * 16 + q * 4 + r;
              ast16(&h1ring[(t & 3) * 65536 + row * 1024 + h_ew], f2bf(Hn));
              if (t == 255) {
                outF[row * 1024 + h_ew] = Hn;           // H1 final
                outF[65536 + row * 1024 + h_ew] = Cn;   // C1 final
              }
            }
          }
        }
      }
      publish_slot(g1slots, myslot, (unsigned)(t + 1));      // H1(t) published

      // prefetch next step's embedding gathers (latency hides under next poll)
      if (kh == 0) {
#pragma unroll
        for (int i = 0; i < 16; ++i)
          gv[i] = W1[(size_t)g * 5242880u + (size_t)tk2[i] * 1024u + hcol];
      }
    }
  } else {
    // ================= G3 chain =================
#pragma clang loop unroll(disable)
    for (int t = 0; t < 256; ++t) {
      // phase C FIRST (early start): H1(t) available since G1 runs ahead
      wait_slots(g1slots, (unsigned)(t + 1), poison);
#pragma unroll
      for (int m = 0; m < 4; ++m)
        acc[m] = (kh == 0) ? (f32x4){biasv, biasv, biasv, biasv}
                           : (f32x4){0.f, 0.f, 0.f, 0.f};
      stage_H(h1ring + (t & 3) * 65536, Hs);
      __syncthreads();
#pragma unroll
      for (int j = 0; j < 16; ++j)
#pragma unroll
        for (int m = 0; m < 4; ++m)
          acc[m] = MFMA16x32(lds_frag(Hs, m * 16 + c, (kh * 16 + j) * 64 + q * 16),
                             Breg[16 + j], acc[m]);

      if (t > 0) {       // phase A: H2(t-1) @ W2h (own-group barrier guards Hs)
        wait_slots(g3slots, (unsigned)t, poison);
        stage_H(h2all + (size_t)(t - 1) * 65536, Hs);
        __syncthreads();
#pragma unroll
        for (int j = 0; j < 16; ++j)
#pragma unroll
          for (int m = 0; m < 4; ++m)
            acc[m] = MFMA16x32(lds_frag(Hs, m * 16 + c, (kh * 16 + j) * 64 + q * 16),
                               Breg[j], acc[m]);
      }

      // K-split partial exchange (lane-major, conflict-free)
      if (kh == 1) {
#pragma unroll
        for (int m = 0; m < 4; ++m)
#pragma unroll
          for (int r = 0; r < 4; ++r) red[ct][m * 4 + r][lane] = acc[m][r];
      }
      __syncthreads();
      if (kh == 0) {
#pragma unroll
        for (int m = 0; m < 4; ++m) {
#pragma unroll
          for (int r = 0; r < 4; ++r) {
            float v = acc[m][r] + red[ct][m * 4 + r][lane];
            const int sb = (lane & 48) | (lane & 3);
            float vf = __shfl(v, sb, 64);
            float vi = __shfl(v, sb | 4, 64);
            float vo = __shfl(v, sb | 8, 64);
            float vc = __shfl(v, sb | 12, 64);
            float fg = 1.f / (1.f + __expf(-vf));
            float ig = 1.f / (1.f + __expf(-vi));
            float og = 1.f / (1.f + __expf(-vo));
            float e2 = __expf(2.f * vc);
            float ct_ = (e2 - 1.f) / (e2 + 1.f);
            float Cn = fg * Cst[m * 4 + r] + ig * ct_;
            Cst[m * 4 + r] = Cn;
            float e2c = __expf(2.f * Cn);
            float Hn = og * (e2c - 1.f) / (e2c + 1.f);
            if ((lane & 12) == 0) {
              int row = m * 16 + q * 4 + r;
              ast16(&h2all[((size_t)t * 64 + row) * 1024 + h_ew], f2bf(Hn));
              if (t == 255) {
                outF[131072 + row * 1024 + h_ew] = Hn;  // H2 final
                outF[196608 + row * 1024 + h_ew] = Cn;  // C2 final
              }
            }
          }
        }
      }
      publish_slot(g3slots, myslot, (unsigned)(t + 1));      // H2(t) published
    }
  }
}

// ---------------- output projection: Y = H2all @ Wout + bout ----------------
__global__ __launch_bounds__(256, 2) void k_gemm_out(
    const unsigned short* __restrict__ A, const unsigned short* __restrict__ Bt,
    const float* __restrict__ bout, float* __restrict__ C)
{
  __shared__ unsigned short As[128 * 32];
  __shared__ unsigned short Bs[128 * 32];
  const int tid = threadIdx.x, lane = tid & 63, wv = tid >> 6;
  const int c = lane & 15, q = lane >> 4;
  const int bn = blockIdx.x & 31, bm = blockIdx.x >> 5;
  const int wm = wv >> 1, wn = wv & 1;

  f32x4 acc[4][4];
#pragma unroll
  for (int m = 0; m < 4; ++m)
#pragma unroll
    for (int n = 0; n < 4; ++n) acc[m][n] = (f32x4){0.f, 0.f, 0.f, 0.f};

  const unsigned short* Abase = A + (size_t)(bm * 128) * 1024;
  const unsigned short* Bbase = Bt + (size_t)(bn * 128) * 1024;

  for (int kt = 0; kt < 32; ++kt) {
    if (kt) __syncthreads();
#pragma unroll
    for (int ch = 0; ch < 2; ++ch) {
      int o = ch * 4096 + tid * 16;
      int row = o >> 6;
      int ks = (o & 63) >> 1;
      *(bf16x8*)&As[o >> 1] = *(const bf16x8*)(Abase + (size_t)row * 1024 + kt * 32 + ks);
      *(bf16x8*)&Bs[o >> 1] = *(const bf16x8*)(Bbase + (size_t)row * 1024 + kt * 32 + ks);
    }
    __syncthreads();
    bf16x8 af[4], bfr[4];
#pragma unroll
    for (int m = 0; m < 4; ++m) af[m] = *(const bf16x8*)&As[(wm * 64 + m * 16 + c) * 32 + q * 8];
#pragma unroll
    for (int n = 0; n < 4; ++n) bfr[n] = *(const bf16x8*)&Bs[(wn * 64 + n * 16 + c) * 32 + q * 8];
#pragma unroll
    for (int m = 0; m < 4; ++m)
#pragma unroll
      for (int n = 0; n < 4; ++n) acc[m][n] = MFMA16x32(af[m], bfr[n], acc[m][n]);
  }

#pragma unroll
  for (int n = 0; n < 4; ++n) {
    int col = bn * 128 + wn * 64 + n * 16 + c;
    float bo = bout[col];
#pragma unroll
    for (int m = 0; m < 4; ++m) {
      int row0 = bm * 128 + wm * 64 + m * 16 + q * 4;
#pragma unroll
      for (int r = 0; r < 4; ++r)
        C[(size_t)(row0 + r) * 4096 + col] = acc[m][n][r] + bo;
    }
  }
}

extern "C" void kernel_launch(void* const* d_in, const int* in_sizes, int n_in,
                              void* d_out, int out_size, void* d_ws, size_t ws_size,
                              hipStream_t stream) {
  const int* tokens = (const int*)d_in[0];
  const float* W1 = (const float*)d_in[1];
  const float* b1 = (const float*)d_in[2];
  const float* W2 = (const float*)d_in[3];
  const float* b2 = (const float*)d_in[4];
  const float* Wout = (const float*)d_in[5];
  const float* bout = (const float*)d_in[6];

  char* ws = (char*)d_ws;
  unsigned short* g1blob = (unsigned short*)(ws + WS_G1BLOB);
  unsigned short* g3blob = (unsigned short*)(ws + WS_G3BLOB);
  unsigned short* woutT  = (unsigned short*)(ws + WS_WOUTT);
  unsigned short* h1ring = (unsigned short*)(ws + WS_H1RING);
  unsigned*       syncb  = (unsigned*)(ws + WS_SYNC);
  unsigned short* h2all  = (unsigned short*)(ws + WS_H2ALL);

  float* outY = (float*)d_out;
  float* outF = outY + 67108864;   // Y then H1,C1,H2,C2

  hipLaunchKernelGGL(k_init, dim3(16), dim3(256), 0, stream, syncb, 4096);
  hipLaunchKernelGGL(k_pack_g1, dim3(2048), dim3(256), 0, stream, W1, g1blob);
  hipLaunchKernelGGL(k_pack_g3, dim3(4096), dim3(256), 0, stream, W2, g3blob);
  hipLaunchKernelGGL(k_pack_woutT, dim3(16384), dim3(256), 0, stream, Wout, woutT);

  hipLaunchKernelGGL(k_lstm, dim3(256), dim3(256), 0, stream,
                     tokens, W1, b1, b2, g1blob, g3blob, h1ring, h2all, outF, syncb);

  hipLaunchKernelGGL(k_gemm_out, dim3(4096), dim3(256), 0, stream, h2all, woutT, bout, outY);
}